// Round 1
// baseline (118.324 us; speedup 1.0000x reference)
//
#include <hip/hip_runtime.h>

// PopulationLayer: lateral = pa @ (W with zeroed diag); v_new = exp(-0.1)*v + ext - lateral;
// out = (v_new > threshold) ? 1 : 0   (straight-through forward == hard)
//
// Output is BINARY -> absmax 0.02 means zero decision flips allowed.
// Strategy: fp64 accumulation everywhere so we match a float64 numpy reference
// to ~1e-13, making boundary flips essentially impossible.

#define PP 4096
#define BB 256

constexpr int ROWS_PER_CHUNK = 64;
constexpr int NCHUNK = PP / ROWS_PER_CHUNK;   // 64
constexpr int COLS_PER_TILE = 1024;
constexpr int NTILE = PP / COLS_PER_TILE;     // 4

// Stage 1: deterministic partial sums. grid = NTILE*NCHUNK = 256 blocks, 256 thr.
// Each thread owns 4 adjacent columns (float4 load), loops 64 rows.
__global__ __launch_bounds__(256)
void lateral_partial(const float* __restrict__ w, const float* __restrict__ pa,
                     double* __restrict__ part) {
    const int tile = blockIdx.x & (NTILE - 1);
    const int rch  = blockIdx.x >> 2;               // NTILE == 4
    const int c    = tile * COLS_PER_TILE + (int)threadIdx.x * 4;
    const int r0   = rch * ROWS_PER_CHUNK;
    double a0 = 0.0, a1 = 0.0, a2 = 0.0, a3 = 0.0;
#pragma unroll 8
    for (int k = 0; k < ROWS_PER_CHUNK; ++k) {
        const int i = r0 + k;
        const double p = (double)pa[i];             // block-uniform -> scalar load
        const float4 wv = *reinterpret_cast<const float4*>(w + (size_t)i * PP + c);
        // diagonal mask: skip i == column
        a0 += (i == c + 0) ? 0.0 : p * (double)wv.x;
        a1 += (i == c + 1) ? 0.0 : p * (double)wv.y;
        a2 += (i == c + 2) ? 0.0 : p * (double)wv.z;
        a3 += (i == c + 3) ? 0.0 : p * (double)wv.w;
    }
    double* dst = part + (size_t)rch * PP + c;
    dst[0] = a0; dst[1] = a1; dst[2] = a2; dst[3] = a3;
}

// Stage 2: reduce 64 partials per column. grid = PP/256 = 16 blocks.
__global__ __launch_bounds__(256)
void lateral_reduce(const double* __restrict__ part, double* __restrict__ lat) {
    const int j = blockIdx.x * 256 + (int)threadIdx.x;
    double s = 0.0;
#pragma unroll 8
    for (int r = 0; r < NCHUNK; ++r) s += part[(size_t)r * PP + j];
    lat[j] = s;
}

// Stage 3: elementwise LIF + hard spike. grid = B*P/(4*256) = 1024 blocks.
__global__ __launch_bounds__(256)
void spike(const float* __restrict__ ext, const float* __restrict__ v,
           const float* __restrict__ thr, const double* __restrict__ lat,
           float* __restrict__ out) {
    const size_t t = ((size_t)blockIdx.x * 256 + threadIdx.x) * 4;
    const int j = (int)(t & (PP - 1));
    const float4 e  = *reinterpret_cast<const float4*>(ext + t);
    const float4 vv = *reinterpret_cast<const float4*>(v + t);
    const float4 th = *reinterpret_cast<const float4*>(thr + t);
    const double l0 = lat[j], l1 = lat[j + 1], l2 = lat[j + 2], l3 = lat[j + 3];
    const double dec = 0.90483741803595952;  // exp(-0.1) in fp64
    float4 o;
    o.x = (dec * (double)vv.x + (double)e.x - l0 > (double)th.x) ? 1.0f : 0.0f;
    o.y = (dec * (double)vv.y + (double)e.y - l1 > (double)th.y) ? 1.0f : 0.0f;
    o.z = (dec * (double)vv.z + (double)e.z - l2 > (double)th.z) ? 1.0f : 0.0f;
    o.w = (dec * (double)vv.w + (double)e.w - l3 > (double)th.w) ? 1.0f : 0.0f;
    *reinterpret_cast<float4*>(out + t) = o;
}

extern "C" void kernel_launch(void* const* d_in, const int* in_sizes, int n_in,
                              void* d_out, int out_size, void* d_ws, size_t ws_size,
                              hipStream_t stream) {
    const float* ext = (const float*)d_in[0];   // [B,P]
    const float* w   = (const float*)d_in[1];   // [P,P]
    const float* pa  = (const float*)d_in[2];   // [P]
    const float* v   = (const float*)d_in[3];   // [B,P]
    const float* thr = (const float*)d_in[4];   // [B,P]
    float* out = (float*)d_out;

    double* part = (double*)d_ws;                       // NCHUNK*PP doubles = 2 MiB
    double* lat  = part + (size_t)NCHUNK * PP;          // PP doubles = 32 KiB

    lateral_partial<<<NTILE * NCHUNK, 256, 0, stream>>>(w, pa, part);
    lateral_reduce<<<PP / 256, 256, 0, stream>>>(part, lat);
    spike<<<(BB * PP) / (4 * 256), 256, 0, stream>>>(ext, v, thr, lat, out);
}

// Round 2
// 112.968 us; speedup vs baseline: 1.0474x; 1.0474x over previous
//
#include <hip/hip_runtime.h>

// PopulationLayer: lateral = pa @ (W with zeroed diag); v_new = exp(-0.1)*v + ext - lateral;
// out = (v_new > threshold) ? 1 : 0   (straight-through forward == hard)
//
// Output is BINARY -> absmax 0.02 means zero decision flips allowed.
// fp64 accumulation everywhere -> matches fp64 numpy ref to ~1e-13 (R1: absmax 0.0).
//
// R2 changes: stage1 1024 blocks (16 waves/CU, was 4), diagonal subtracted in
// reduce instead of predicated per-iter, reduce widened to 64 blocks.

#define PP 4096
#define BB 256

constexpr int ROWS_PER_CHUNK = 16;
constexpr int NCHUNK = PP / ROWS_PER_CHUNK;   // 256
constexpr int COLS_PER_TILE = 1024;
constexpr int NTILE = PP / COLS_PER_TILE;     // 4

// Stage 1: deterministic partial sums. grid = NTILE*NCHUNK = 1024 blocks, 256 thr.
// Each thread owns 4 adjacent columns (float4 load), 16 rows, fully unrolled.
__global__ __launch_bounds__(256)
void lateral_partial(const float* __restrict__ w, const float* __restrict__ pa,
                     double* __restrict__ part) {
    const int tile = blockIdx.x & (NTILE - 1);
    const int rch  = blockIdx.x >> 2;               // NTILE == 4
    const int c    = tile * COLS_PER_TILE + (int)threadIdx.x * 4;
    const int r0   = rch * ROWS_PER_CHUNK;
    double a0 = 0.0, a1 = 0.0, a2 = 0.0, a3 = 0.0;
#pragma unroll
    for (int k = 0; k < ROWS_PER_CHUNK; ++k) {
        const int i = r0 + k;
        const double p = (double)pa[i];             // block-uniform -> scalar load
        const float4 wv = *reinterpret_cast<const float4*>(w + (size_t)i * PP + c);
        a0 += p * (double)wv.x;
        a1 += p * (double)wv.y;
        a2 += p * (double)wv.z;
        a3 += p * (double)wv.w;
    }
    double* dst = part + (size_t)rch * PP + c;
    *reinterpret_cast<double2*>(dst)     = make_double2(a0, a1);
    *reinterpret_cast<double2*>(dst + 2) = make_double2(a2, a3);
}

// Stage 2: reduce NCHUNK partials per column, subtract diagonal term.
// grid = PP/64 = 64 blocks; 256 thr = 64 cols x 4 row-groups; LDS combine.
__global__ __launch_bounds__(256)
void lateral_reduce(const double* __restrict__ part, const float* __restrict__ w,
                    const float* __restrict__ pa, double* __restrict__ lat) {
    __shared__ double sh[256];
    const int lane = (int)threadIdx.x & 63;
    const int grp  = (int)threadIdx.x >> 6;
    const int col  = blockIdx.x * 64 + lane;
    double s = 0.0;
    const int rbase = grp * (NCHUNK / 4);
#pragma unroll 16
    for (int r = 0; r < NCHUNK / 4; ++r)
        s += part[(size_t)(rbase + r) * PP + col];
    sh[threadIdx.x] = s;
    __syncthreads();
    if (grp == 0) {
        double t = sh[lane] + sh[64 + lane] + sh[128 + lane] + sh[192 + lane];
        // remove self-connection: the full sum included pa[col]*W[col,col]
        t -= (double)pa[col] * (double)w[(size_t)col * (PP + 1)];
        lat[col] = t;
    }
}

// Stage 3: elementwise LIF + hard spike. grid = B*P/(4*256) = 1024 blocks.
__global__ __launch_bounds__(256)
void spike(const float* __restrict__ ext, const float* __restrict__ v,
           const float* __restrict__ thr, const double* __restrict__ lat,
           float* __restrict__ out) {
    const size_t t = ((size_t)blockIdx.x * 256 + threadIdx.x) * 4;
    const int j = (int)(t & (PP - 1));
    const float4 e  = *reinterpret_cast<const float4*>(ext + t);
    const float4 vv = *reinterpret_cast<const float4*>(v + t);
    const float4 th = *reinterpret_cast<const float4*>(thr + t);
    const double l0 = lat[j], l1 = lat[j + 1], l2 = lat[j + 2], l3 = lat[j + 3];
    const double dec = 0.90483741803595952;  // exp(-0.1) in fp64
    float4 o;
    o.x = (dec * (double)vv.x + (double)e.x - l0 > (double)th.x) ? 1.0f : 0.0f;
    o.y = (dec * (double)vv.y + (double)e.y - l1 > (double)th.y) ? 1.0f : 0.0f;
    o.z = (dec * (double)vv.z + (double)e.z - l2 > (double)th.z) ? 1.0f : 0.0f;
    o.w = (dec * (double)vv.w + (double)e.w - l3 > (double)th.w) ? 1.0f : 0.0f;
    *reinterpret_cast<float4*>(out + t) = o;
}

extern "C" void kernel_launch(void* const* d_in, const int* in_sizes, int n_in,
                              void* d_out, int out_size, void* d_ws, size_t ws_size,
                              hipStream_t stream) {
    const float* ext = (const float*)d_in[0];   // [B,P]
    const float* w   = (const float*)d_in[1];   // [P,P]
    const float* pa  = (const float*)d_in[2];   // [P]
    const float* v   = (const float*)d_in[3];   // [B,P]
    const float* thr = (const float*)d_in[4];   // [B,P]
    float* out = (float*)d_out;

    double* part = (double*)d_ws;                       // NCHUNK*PP doubles = 8 MiB
    double* lat  = part + (size_t)NCHUNK * PP;          // PP doubles = 32 KiB

    lateral_partial<<<NTILE * NCHUNK, 256, 0, stream>>>(w, pa, part);
    lateral_reduce<<<PP / 64, 256, 0, stream>>>(part, w, pa, lat);
    spike<<<(BB * PP) / (4 * 256), 256, 0, stream>>>(ext, v, thr, lat, out);
}